// Round 1
// 441.659 us; speedup vs baseline: 1.0207x; 1.0207x over previous
//
#include <hip/hip_runtime.h>
#include <hip/hip_bf16.h>
#include <math.h>

#define NN 50000
#define DD 128
#define RR 16
#define NBASIS 10
#define NE 1600000
#define NSEG (NN * RR)                  // 800000 segments (dst,rel)
#define NPART ((NSEG + 1023) / 1024)    // 782
#define NSLICE 12                       // 10 basis + time + root  (basis-space compressed)
#define KTOT (NSLICE * DD)              // 1536
#define DECAY 0.1f

typedef short bf16x8 __attribute__((ext_vector_type(8)));
typedef float f32x4 __attribute__((ext_vector_type(4)));
typedef float f32x2 __attribute__((ext_vector_type(2)));

__device__ __forceinline__ ushort f2b(float f) {
    unsigned u = __float_as_uint(f);
    unsigned r = (u + 0x7FFFu + ((u >> 16) & 1u)) >> 16;
    return (ushort)r;
}

// ---------------- reduction slots ----------------
__global__ void k_init(unsigned* red) {
    if (threadIdx.x == 0) {
        red[0] = 0u;              // max(t) bits (t>=0: uint order == float order)
        red[1] = 0x7F800000u;     // min(t) = +inf
        ((float*)red)[2] = 0.0f;  // sum of unnormalized w
    }
}

// ---------------- grid-stride: edge_time min/max + segment histogram ----------------
__global__ __launch_bounds__(256) void k_pre1(const float* __restrict__ t,
                                              const int* __restrict__ edst,
                                              const int* __restrict__ etype,
                                              unsigned* __restrict__ red,
                                              unsigned* __restrict__ cnt) {
    __shared__ float smx[4], smn[4];
    const int tid = threadIdx.x;
    float mx = 0.0f, mn = 1e30f;
    const int stride = gridDim.x * 256;
    for (int e = blockIdx.x * 256 + tid; e < NE; e += stride) {
        float v = __builtin_nontemporal_load(t + e);
        int d   = __builtin_nontemporal_load(edst + e);
        int ty  = __builtin_nontemporal_load(etype + e);
        mx = fmaxf(mx, v);
        mn = fminf(mn, v);
        atomicAdd(&cnt[d * RR + ty], 1u);
    }
    for (int o = 32; o >= 1; o >>= 1) {
        mx = fmaxf(mx, __shfl_down(mx, o, 64));
        mn = fminf(mn, __shfl_down(mn, o, 64));
    }
    if ((tid & 63) == 0) { smx[tid >> 6] = mx; smn[tid >> 6] = mn; }
    __syncthreads();
    if (tid == 0) {
        mx = fmaxf(fmaxf(smx[0], smx[1]), fmaxf(smx[2], smx[3]));
        mn = fminf(fminf(smn[0], smn[1]), fminf(smn[2], smn[3]));
        atomicMax(&red[0], __float_as_uint(mx));
        atomicMin(&red[1], __float_as_uint(mn));
    }
}

// ---------------- hierarchical exclusive scan over cnt[NSEG] ----------------
__global__ __launch_bounds__(1024) void k_scan1(const unsigned* __restrict__ cnt,
                                                unsigned* __restrict__ segptr,
                                                unsigned* __restrict__ part) {
    __shared__ unsigned sh[1024];
    int tid = threadIdx.x;
    int i = blockIdx.x * 1024 + tid;
    unsigned v = (i < NSEG) ? cnt[i] : 0u;
    sh[tid] = v;
    __syncthreads();
    for (int off = 1; off < 1024; off <<= 1) {
        unsigned t = (tid >= off) ? sh[tid - off] : 0u;
        __syncthreads();
        sh[tid] += t;
        __syncthreads();
    }
    if (i < NSEG) segptr[i] = sh[tid] - v;       // exclusive, block-local
    if (tid == 1023) part[blockIdx.x] = sh[1023];
}

__global__ __launch_bounds__(1024) void k_scan2(unsigned* __restrict__ part) {
    __shared__ unsigned sh[1024];
    int tid = threadIdx.x;
    unsigned v = (tid < NPART) ? part[tid] : 0u;
    sh[tid] = v;
    __syncthreads();
    for (int off = 1; off < 1024; off <<= 1) {
        unsigned t = (tid >= off) ? sh[tid - off] : 0u;
        __syncthreads();
        sh[tid] += t;
        __syncthreads();
    }
    if (tid < NPART) part[tid] = sh[tid] - v;    // exclusive
}

__global__ __launch_bounds__(1024) void k_scan3(unsigned* __restrict__ segptr,
                                                const unsigned* __restrict__ part) {
    int i = blockIdx.x * 1024 + threadIdx.x;
    if (i < NSEG) segptr[i] += part[i >> 10];
}

// ---------------- grid-stride: sum of weights + reorder into packed records ----------------
__global__ __launch_bounds__(256) void k_pre2(const int* __restrict__ esrc,
                                              const int* __restrict__ edst,
                                              const int* __restrict__ etype,
                                              const float* __restrict__ etime,
                                              unsigned* __restrict__ red,
                                              unsigned* __restrict__ segptr,
                                              unsigned* __restrict__ srcw) {
    __shared__ float ssum[4];
    const int tid = threadIdx.x;
    const float tmax = __uint_as_float(red[0]);
    const float tmin = __uint_as_float(red[1]);
    const float rtd = -DECAY / (tmax - tmin + 1e-8f);
    float s = 0.0f;
    const int stride = gridDim.x * 256;
    for (int e = blockIdx.x * 256 + tid; e < NE; e += stride) {
        float tv = __builtin_nontemporal_load(etime + e);
        int sv   = __builtin_nontemporal_load(esrc + e);
        int dv   = __builtin_nontemporal_load(edst + e);
        int yv   = __builtin_nontemporal_load(etype + e);
        float w = __expf((tmax - tv) * rtd);     // arg in [-0.1,0]: fast path safe
        s += w;
        int seg = dv * RR + yv;
        unsigned pos = atomicAdd(&segptr[seg], 1u);
        srcw[pos] = (unsigned)(sv & 0xFFFF) | ((unsigned)f2b(w) << 16);
    }
    for (int o = 32; o >= 1; o >>= 1) s += __shfl_down(s, o, 64);
    if ((tid & 63) == 0) ssum[tid >> 6] = s;
    __syncthreads();
    if (tid == 0)
        atomicAdd(((float*)red) + 2, ssum[0] + ssum[1] + ssum[2] + ssum[3]);
}

// ---------------- fused: x->bf16 and build Bt3[j][k] bf16 (k = slice*128+d) ----------------
// Basis-compressed B: slices 0..9 = basis[b] (no comp mixing), 10 = tp_w, 11 = root.
#define XB_ITEMS (NN * (DD / 4))
__global__ __launch_bounds__(256) void k_prep(const float* __restrict__ x,
                                              const float* __restrict__ basis,
                                              const float* __restrict__ root,
                                              const float* __restrict__ tp_w,
                                              ushort* __restrict__ xb,
                                              ushort* __restrict__ Bt3) {
    int idx = blockIdx.x * 256 + threadIdx.x;
    if (idx < XB_ITEMS) {
        float4 v = ((const float4*)x)[idx];
        ushort4 o;
        o.x = f2b(v.x); o.y = f2b(v.y); o.z = f2b(v.z); o.w = f2b(v.w);
        ((ushort4*)xb)[idx] = o;
        return;
    }
    int bidx = idx - XB_ITEMS;
    if (bidx >= DD * KTOT) return;
    int j = bidx / KTOT, k = bidx - j * KTOT;
    int s = k >> 7, d = k & 127;
    float v;
    if (s < NBASIS) {
        v = basis[(s * DD + d) * DD + j];
    } else if (s == NBASIS) {
        v = tp_w[d * DD + j];
    } else {
        v = root[d * DD + j];
    }
    Bt3[bidx] = f2b(v);
}

// ---------------- gather-aggregate: one wave per dst, comp-mixed in-register ----------------
// Per relation flush: C[b] += comp[r,b] * mean_r  (10 f32x2 accumulators),
// written once as 10 bf16 slices + time + root  => A2 row of 12*128.
__global__ __launch_bounds__(256) void k_gather(
    const ushort* __restrict__ xb, const unsigned* __restrict__ srcw,
    const unsigned* __restrict__ segptr, const unsigned* __restrict__ red,
    const float* __restrict__ comp,
    ushort* __restrict__ A2)
{
    const int wave = threadIdx.x >> 6, lane = threadIdx.x & 63;
    int dst0 = blockIdx.x * 4 + wave;
    if (dst0 >= NN) return;
    const int dst = __builtin_amdgcn_readfirstlane(dst0);
    const float sumw = ((const float*)red)[2];
    const unsigned s0 = (unsigned)dst * RR;
    const unsigned start = (dst == 0) ? 0u : segptr[s0 - 1];
    const unsigned endAll = segptr[s0 + RR - 1];
    const unsigned deg = endAll - start;
    unsigned* arow = (unsigned*)(A2 + (size_t)dst * KTOT);

    f32x2 cb[NBASIS];
#pragma unroll
    for (int b = 0; b < NBASIS; ++b) cb[b] = (f32x2){0.f, 0.f};
    f32x2 acc = {0.f, 0.f}, xt = {0.f, 0.f};

    int r = 0;
    unsigned scur = start;
    unsigned endr = segptr[s0];
    unsigned e = start;

#define FLUSH_REL {                                                          \
        float scl = (endr > scur) ? (1.0f / (float)(endr - scur)) : 0.0f;    \
        f32x2 t = acc * scl;                                                 \
        _Pragma("unroll")                                                    \
        for (int b = 0; b < NBASIS; ++b)                                     \
            cb[b] += t * comp[r * NBASIS + b];                               \
        acc = (f32x2){0.f, 0.f}; scur = endr; ++r;                           \
        endr = (r < RR) ? segptr[s0 + r] : 0xFFFFFFFFu; }

#define ACCUM(rec, pv) {                                                     \
        float wgt = __uint_as_float((rec) & 0xFFFF0000u);                    \
        f32x2 v;                                                             \
        v.x = __uint_as_float((pv) << 16);                                   \
        v.y = __uint_as_float((pv) & 0xFFFF0000u);                           \
        acc += v;                                                            \
        xt += v * wgt; }

    while (e < endAll) {
        unsigned rem = endAll - e;
        int m = (rem > 4u) ? 4 : (int)rem;
        unsigned rec0 = 0, rec1 = 0, rec2 = 0, rec3 = 0;
        unsigned pv0 = 0, pv1 = 0, pv2 = 0, pv3 = 0;
        rec0 = srcw[e];
        if (m > 1) rec1 = srcw[e + 1];
        if (m > 2) rec2 = srcw[e + 2];
        if (m > 3) rec3 = srcw[e + 3];
        pv0 = ((const unsigned*)(xb + (size_t)(rec0 & 0xFFFFu) * DD))[lane];
        if (m > 1) pv1 = ((const unsigned*)(xb + (size_t)(rec1 & 0xFFFFu) * DD))[lane];
        if (m > 2) pv2 = ((const unsigned*)(xb + (size_t)(rec2 & 0xFFFFu) * DD))[lane];
        if (m > 3) pv3 = ((const unsigned*)(xb + (size_t)(rec3 & 0xFFFFu) * DD))[lane];

        while (e >= endr) FLUSH_REL;
        ACCUM(rec0, pv0); ++e;
        if (m > 1) { while (e >= endr) FLUSH_REL; ACCUM(rec1, pv1); ++e; }
        if (m > 2) { while (e >= endr) FLUSH_REL; ACCUM(rec2, pv2); ++e; }
        if (m > 3) { while (e >= endr) FLUSH_REL; ACCUM(rec3, pv3); ++e; }
    }
    while (r < RR) FLUSH_REL;

#pragma unroll
    for (int b = 0; b < NBASIS; ++b)
        __builtin_nontemporal_store(
            (unsigned)f2b(cb[b].x) | ((unsigned)f2b(cb[b].y) << 16),
            arow + b * 64 + lane);

    float s2 = 1.0f / ((sumw + 1e-8f) * fmaxf((float)deg, 1.0f));
    __builtin_nontemporal_store(
        (unsigned)f2b(xt.x * s2) | ((unsigned)f2b(xt.y * s2) << 16),
        arow + NBASIS * 64 + lane);
    __builtin_nontemporal_store(
        ((const unsigned*)(xb + (size_t)dst * DD))[lane],
        arow + (NBASIS + 1) * 64 + lane);
#undef FLUSH_REL
#undef ACCUM
}

// ---------------- tiled MFMA GEMM: double-buffered B in LDS, A register-prefetched ----------
// 2-phase pipeline: stage B(it+1) into buf^1, compute buf, ONE barrier/iter.
// Staging latency (and the A prefetch) hide under a full iteration of ds_read+MFMA.
__global__ __launch_bounds__(256) void k_fgemm(
    const ushort* __restrict__ A2, const ushort* __restrict__ Bt3,
    const float* __restrict__ bias, const float* __restrict__ tpb,
    const float* __restrict__ gamma, const float* __restrict__ beta,
    float* __restrict__ out)
{
    __shared__ unsigned Bs[2][4096];    // 2 x 16 KB: [col 128][8 chunks x 16B], XOR-swizzled

    const int tid = threadIdx.x;
    const int w = tid >> 6, lane = tid & 63;
    const int quad = lane >> 4, l16 = lane & 15;
    const int n0 = blockIdx.x * 64;

    f32x4 acc[8];
#pragma unroll
    for (int ct = 0; ct < 8; ++ct) acc[ct] = (f32x4){0.f, 0.f, 0.f, 0.f};

    const ushort* arow = A2 + (size_t)(n0 + w * 16 + l16) * KTOT + quad * 8;
    const int srow = lane >> 3;          // 0..7 within a staging inst group
    const int sc   = lane & 7;           // physical chunk

#define STAGE(buf, itv) {                                                    \
        const int k0_ = (itv) * 64;                                          \
        _Pragma("unroll")                                                    \
        for (int i_ = 0; i_ < 4; ++i_) {                                     \
            const int cid_ = i_ * 4 + w;                                     \
            const int row_ = cid_ * 8 + srow;                                \
            const int ck_  = sc ^ (row_ & 7);                                \
            const ushort* gb_ = Bt3 + (size_t)row_ * KTOT + k0_ + ck_ * 8;   \
            __builtin_amdgcn_global_load_lds(                                \
                (const __attribute__((address_space(1))) unsigned*)gb_,      \
                (__attribute__((address_space(3))) unsigned*)&Bs[buf][cid_ * 256], \
                16, 0, 0);                                                   \
        } }

    STAGE(0, 0);
    bf16x8 afp0 = *(const bf16x8*)(arow);         // prefetch A(it=0)
    bf16x8 afp1 = *(const bf16x8*)(arow + 32);
    __syncthreads();                              // drain stage(0) + A(0)

    const int NIT = KTOT / 64;                    // 24
    for (int it = 0; it < NIT; ++it) {
        if (it + 1 < NIT) STAGE((it + 1) & 1, it + 1);   // overlaps compute below
        bf16x8 af0 = afp0, af1 = afp1;
        if (it + 1 < NIT) {                       // prefetch A(it+1)
            afp0 = *(const bf16x8*)(arow + (it + 1) * 64);
            afp1 = *(const bf16x8*)(arow + (it + 1) * 64 + 32);
        }
        const unsigned* Bp = &Bs[it & 1][0];
#pragma unroll
        for (int ct = 0; ct < 8; ++ct) {
            const int rB = ct * 16 + l16;
            bf16x8 b0 = *(const bf16x8*)&Bp[rB * 32 + ((quad ^ (rB & 7)) << 2)];
            bf16x8 b1 = *(const bf16x8*)&Bp[rB * 32 + (((4 + quad) ^ (rB & 7)) << 2)];
            acc[ct] = __builtin_amdgcn_mfma_f32_16x16x32_bf16(af0, b0, acc[ct], 0, 0, 0);
            acc[ct] = __builtin_amdgcn_mfma_f32_16x16x32_bf16(af1, b1, acc[ct], 0, 0, 0);
        }
        __syncthreads();   // drains stage(it+1)+A(it+1); all waves done reading Bs[it&1]
    }
#undef STAGE

    // ---- epilogue: bias + relu + LN (in-wave, rows rb = n0 + w*16) ----
    float bc[8], gc[8], be[8];
#pragma unroll
    for (int ct = 0; ct < 8; ++ct) {
        int col = ct * 16 + l16;
        bc[ct] = bias[col] + tpb[col];
        gc[ct] = gamma[col];
        be[ct] = beta[col];
    }
    float s[4] = {0, 0, 0, 0}, q[4] = {0, 0, 0, 0};
#pragma unroll
    for (int ct = 0; ct < 8; ++ct)
#pragma unroll
        for (int i = 0; i < 4; ++i) {
            float v = fmaxf(acc[ct][i] + bc[ct], 0.0f);
            acc[ct][i] = v;
            s[i] += v;
            q[i] = fmaf(v, v, q[i]);
        }
#pragma unroll
    for (int off = 1; off < 16; off <<= 1)
#pragma unroll
        for (int i = 0; i < 4; ++i) {
            s[i] += __shfl_xor(s[i], off, 64);
            q[i] += __shfl_xor(q[i], off, 64);
        }
#pragma unroll
    for (int i = 0; i < 4; ++i) {
        const int row = n0 + w * 16 + quad * 4 + i;
        float mu  = s[i] * (1.0f / DD);
        float var = q[i] * (1.0f / DD) - mu * mu;
        float inv = rsqrtf(var + 1e-5f);
        if (row < NN) {
#pragma unroll
            for (int ct = 0; ct < 8; ++ct)
                __builtin_nontemporal_store(
                    (acc[ct][i] - mu) * inv * gc[ct] + be[ct],
                    out + (size_t)row * DD + ct * 16 + l16);
        }
    }
}

extern "C" void kernel_launch(void* const* d_in, const int* in_sizes, int n_in,
                              void* d_out, int out_size, void* d_ws, size_t ws_size,
                              hipStream_t stream)
{
    const float* x     = (const float*)d_in[0];
    const int*   ei    = (const int*)d_in[1];
    const int*   etype = (const int*)d_in[2];
    const float* etime = (const float*)d_in[3];
    const float* basis = (const float*)d_in[4];
    const float* comp  = (const float*)d_in[5];
    const float* root  = (const float*)d_in[6];
    const float* bias  = (const float*)d_in[7];
    const float* tp_w  = (const float*)d_in[8];
    const float* tp_b  = (const float*)d_in[9];
    const float* gamma = (const float*)d_in[10];
    const float* beta  = (const float*)d_in[11];
    float* out = (float*)d_out;

    char* ws = (char*)d_ws;
    size_t off = 0;
    auto alloc = [&](size_t bytes) -> void* {
        void* p = ws + off;
        off = (off + bytes + 255) & ~(size_t)255;
        return p;
    };
    unsigned* red    = (unsigned*)alloc(64);
    unsigned* cnt    = (unsigned*)alloc((size_t)NSEG * 4);        //   3.2 MB
    unsigned* segptr = (unsigned*)alloc((size_t)NSEG * 4);        //   3.2 MB
    unsigned* part   = (unsigned*)alloc(1024 * 4);                //   4 KB
    unsigned* srcw   = (unsigned*)alloc((size_t)NE * 4);          //   6.4 MB
    ushort*   xb     = (ushort*)alloc((size_t)NN * DD * 2);       //  12.8 MB
    ushort*   Bt3    = (ushort*)alloc((size_t)DD * KTOT * 2);     //   0.39 MB
    ushort*   A2     = (ushort*)alloc((size_t)50048 * KTOT * 2);  // 153.7 MB (~180 MB total)
    (void)ws_size;

    const int* esrc = ei;
    const int* edst = ei + NE;

    hipLaunchKernelGGL(k_init, dim3(1), dim3(64), 0, stream, red);
    (void)hipMemsetAsync(cnt, 0, (size_t)NSEG * 4, stream);
    hipLaunchKernelGGL(k_pre1, dim3(1024), dim3(256), 0, stream,
                       etime, edst, etype, red, cnt);

    hipLaunchKernelGGL(k_scan1, dim3(NPART), dim3(1024), 0, stream, cnt, segptr, part);
    hipLaunchKernelGGL(k_scan2, dim3(1), dim3(1024), 0, stream, part);
    hipLaunchKernelGGL(k_scan3, dim3(NPART), dim3(1024), 0, stream, segptr, part);

    hipLaunchKernelGGL(k_pre2, dim3(1024), dim3(256), 0, stream,
                       esrc, edst, etype, etime, red, segptr, srcw);

    hipLaunchKernelGGL(k_prep, dim3((XB_ITEMS + DD * KTOT + 255) / 256), dim3(256), 0, stream,
                       x, basis, root, tp_w, xb, Bt3);

    hipLaunchKernelGGL(k_gather, dim3((NN + 3) / 4), dim3(256), 0, stream,
                       xb, srcw, segptr, red, comp, A2);

    hipLaunchKernelGGL(k_fgemm, dim3((50048 + 63) / 64), dim3(256), 0, stream,
                       A2, Bt3, bias, tp_b, gamma, beta, out);
}

// Round 2
// 421.309 us; speedup vs baseline: 1.0700x; 1.0483x over previous
//
#include <hip/hip_runtime.h>
#include <hip/hip_bf16.h>
#include <math.h>

#define NN 50000
#define DD 128
#define RR 16
#define NBASIS 10
#define NE 1600000
#define NSEG (NN * RR)                  // 800000 segments (dst,rel)
#define NPART ((NSEG + 1023) / 1024)    // 782
#define NSLICE 12                       // 10 basis + time + root  (basis-space compressed)
#define KTOT (NSLICE * DD)              // 1536
#define DECAY 0.1f

typedef short bf16x8 __attribute__((ext_vector_type(8)));
typedef float f32x4 __attribute__((ext_vector_type(4)));
typedef float f32x2 __attribute__((ext_vector_type(2)));

__device__ __forceinline__ ushort f2b(float f) {
    unsigned u = __float_as_uint(f);
    unsigned r = (u + 0x7FFFu + ((u >> 16) & 1u)) >> 16;
    return (ushort)r;
}
// packed f32->bf16 RNE convert (gfx950), lo -> bits[15:0], hi -> bits[31:16]
__device__ __forceinline__ unsigned cvt_pk_bf16(float lo, float hi) {
    unsigned r;
    asm("v_cvt_pk_bf16_f32 %0, %1, %2" : "=v"(r) : "v"(lo), "v"(hi));
    return r;
}

// ---------------- reduction slots ----------------
__global__ void k_init(unsigned* red) {
    if (threadIdx.x == 0) {
        red[0] = 0u;              // max(t) bits (t>=0: uint order == float order)
        red[1] = 0x7F800000u;     // min(t) = +inf
        ((float*)red)[2] = 0.0f;  // sum of unnormalized w
    }
}

// ---------------- grid-stride: edge_time min/max + segment histogram ----------------
__global__ __launch_bounds__(256) void k_pre1(const float* __restrict__ t,
                                              const int* __restrict__ edst,
                                              const int* __restrict__ etype,
                                              unsigned* __restrict__ red,
                                              unsigned* __restrict__ cnt) {
    __shared__ float smx[4], smn[4];
    const int tid = threadIdx.x;
    float mx = 0.0f, mn = 1e30f;
    const int stride = gridDim.x * 256;
    for (int e = blockIdx.x * 256 + tid; e < NE; e += stride) {
        float v = __builtin_nontemporal_load(t + e);
        int d   = __builtin_nontemporal_load(edst + e);
        int ty  = __builtin_nontemporal_load(etype + e);
        mx = fmaxf(mx, v);
        mn = fminf(mn, v);
        atomicAdd(&cnt[d * RR + ty], 1u);
    }
    for (int o = 32; o >= 1; o >>= 1) {
        mx = fmaxf(mx, __shfl_down(mx, o, 64));
        mn = fminf(mn, __shfl_down(mn, o, 64));
    }
    if ((tid & 63) == 0) { smx[tid >> 6] = mx; smn[tid >> 6] = mn; }
    __syncthreads();
    if (tid == 0) {
        mx = fmaxf(fmaxf(smx[0], smx[1]), fmaxf(smx[2], smx[3]));
        mn = fminf(fminf(smn[0], smn[1]), fminf(smn[2], smn[3]));
        atomicMax(&red[0], __float_as_uint(mx));
        atomicMin(&red[1], __float_as_uint(mn));
    }
}

// ---------------- hierarchical exclusive scan over cnt[NSEG] ----------------
__global__ __launch_bounds__(1024) void k_scan1(const unsigned* __restrict__ cnt,
                                                unsigned* __restrict__ segptr,
                                                unsigned* __restrict__ part) {
    __shared__ unsigned sh[1024];
    int tid = threadIdx.x;
    int i = blockIdx.x * 1024 + tid;
    unsigned v = (i < NSEG) ? cnt[i] : 0u;
    sh[tid] = v;
    __syncthreads();
    for (int off = 1; off < 1024; off <<= 1) {
        unsigned t = (tid >= off) ? sh[tid - off] : 0u;
        __syncthreads();
        sh[tid] += t;
        __syncthreads();
    }
    if (i < NSEG) segptr[i] = sh[tid] - v;       // exclusive, block-local
    if (tid == 1023) part[blockIdx.x] = sh[1023];
}

__global__ __launch_bounds__(1024) void k_scan2(unsigned* __restrict__ part) {
    __shared__ unsigned sh[1024];
    int tid = threadIdx.x;
    unsigned v = (tid < NPART) ? part[tid] : 0u;
    sh[tid] = v;
    __syncthreads();
    for (int off = 1; off < 1024; off <<= 1) {
        unsigned t = (tid >= off) ? sh[tid - off] : 0u;
        __syncthreads();
        sh[tid] += t;
        __syncthreads();
    }
    if (tid < NPART) part[tid] = sh[tid] - v;    // exclusive
}

__global__ __launch_bounds__(1024) void k_scan3(unsigned* __restrict__ segptr,
                                                const unsigned* __restrict__ part) {
    int i = blockIdx.x * 1024 + threadIdx.x;
    if (i < NSEG) segptr[i] += part[i >> 10];
}

// ---------------- grid-stride: sum of weights + reorder into packed records ----------------
__global__ __launch_bounds__(256) void k_pre2(const int* __restrict__ esrc,
                                              const int* __restrict__ edst,
                                              const int* __restrict__ etype,
                                              const float* __restrict__ etime,
                                              unsigned* __restrict__ red,
                                              unsigned* __restrict__ segptr,
                                              unsigned* __restrict__ srcw) {
    __shared__ float ssum[4];
    const int tid = threadIdx.x;
    const float tmax = __uint_as_float(red[0]);
    const float tmin = __uint_as_float(red[1]);
    const float rtd = -DECAY / (tmax - tmin + 1e-8f);
    float s = 0.0f;
    const int stride = gridDim.x * 256;
    for (int e = blockIdx.x * 256 + tid; e < NE; e += stride) {
        float tv = __builtin_nontemporal_load(etime + e);
        int sv   = __builtin_nontemporal_load(esrc + e);
        int dv   = __builtin_nontemporal_load(edst + e);
        int yv   = __builtin_nontemporal_load(etype + e);
        float w = __expf((tmax - tv) * rtd);     // arg in [-0.1,0]: fast path safe
        s += w;
        int seg = dv * RR + yv;
        unsigned pos = atomicAdd(&segptr[seg], 1u);
        srcw[pos] = (unsigned)(sv & 0xFFFF) | ((unsigned)f2b(w) << 16);
    }
    for (int o = 32; o >= 1; o >>= 1) s += __shfl_down(s, o, 64);
    if ((tid & 63) == 0) ssum[tid >> 6] = s;
    __syncthreads();
    if (tid == 0)
        atomicAdd(((float*)red) + 2, ssum[0] + ssum[1] + ssum[2] + ssum[3]);
}

// ---------------- fused: x->bf16 and build Bt3[j][k] bf16 (k = slice*128+d) ----------------
// Basis-compressed B: slices 0..9 = basis[b] (no comp mixing), 10 = tp_w, 11 = root.
#define XB_ITEMS (NN * (DD / 4))
__global__ __launch_bounds__(256) void k_prep(const float* __restrict__ x,
                                              const float* __restrict__ basis,
                                              const float* __restrict__ root,
                                              const float* __restrict__ tp_w,
                                              ushort* __restrict__ xb,
                                              ushort* __restrict__ Bt3) {
    int idx = blockIdx.x * 256 + threadIdx.x;
    if (idx < XB_ITEMS) {
        float4 v = ((const float4*)x)[idx];
        uint2 o;
        o.x = cvt_pk_bf16(v.x, v.y);
        o.y = cvt_pk_bf16(v.z, v.w);
        ((uint2*)xb)[idx] = o;
        return;
    }
    int bidx = idx - XB_ITEMS;
    if (bidx >= DD * KTOT) return;
    int j = bidx / KTOT, k = bidx - j * KTOT;
    int s = k >> 7, d = k & 127;
    float v;
    if (s < NBASIS) {
        v = basis[(s * DD + d) * DD + j];
    } else if (s == NBASIS) {
        v = tp_w[d * DD + j];
    } else {
        v = root[d * DD + j];
    }
    Bt3[bidx] = f2b(v);
}

// ---------------- gather-aggregate: one wave per dst, SCALAR bookkeeping ----------------
// Records cooperatively loaded 64-at-a-time, broadcast via v_readlane into SGPRs:
// all record/weight/address math is SALU; VALU only does the payload
// (1 v_add for the 32-bit offset, unpack 2, pk_add, pk_fma per edge).
__global__ __launch_bounds__(256) void k_gather(
    const ushort* __restrict__ xb, const unsigned* __restrict__ srcw,
    const unsigned* __restrict__ segptr, const unsigned* __restrict__ red,
    const float* __restrict__ comp,
    ushort* __restrict__ A2)
{
    const int wave = threadIdx.x >> 6, lane = threadIdx.x & 63;
    int dst0 = blockIdx.x * 4 + wave;
    if (dst0 >= NN) return;
    const int dst = __builtin_amdgcn_readfirstlane(dst0);
    const float sumw = ((const float*)red)[2];
    const unsigned s0 = (unsigned)dst * RR;
    const unsigned start = (dst == 0) ? 0u : segptr[s0 - 1];
    const unsigned endAll = segptr[s0 + RR - 1];
    const unsigned deg = endAll - start;
    unsigned* arow = (unsigned*)(A2 + (size_t)dst * KTOT);
    const unsigned* xbu = (const unsigned*)xb;    // 32-bit dword offsets from here

    f32x2 cb[NBASIS];
#pragma unroll
    for (int b = 0; b < NBASIS; ++b) cb[b] = (f32x2){0.f, 0.f};
    f32x2 acc = {0.f, 0.f}, xt = {0.f, 0.f};

    int r = 0;
    unsigned scur = start;
    unsigned endr = segptr[s0];
    unsigned e = start;

#define FLUSH_REL {                                                          \
        float scl = (endr > scur) ? (1.0f / (float)(endr - scur)) : 0.0f;    \
        f32x2 t = acc * scl;                                                 \
        _Pragma("unroll")                                                    \
        for (int b = 0; b < NBASIS; ++b)                                     \
            cb[b] += t * comp[r * NBASIS + b];                               \
        acc = (f32x2){0.f, 0.f}; scur = endr; ++r;                           \
        endr = (r < RR) ? segptr[s0 + r] : 0xFFFFFFFFu; }

#define ACCUM(recq, pvq) {                                                   \
        float wgt = __uint_as_float((recq) & 0xFFFF0000u);                   \
        f32x2 v;                                                             \
        v.x = __uint_as_float((pvq) << 16);                                  \
        v.y = __uint_as_float((pvq) & 0xFFFF0000u);                          \
        acc += v;                                                            \
        xt += v * wgt; }

    while (e < endAll) {
        unsigned idx = e + (unsigned)lane;
        unsigned recv = srcw[(idx < endAll) ? idx : (endAll - 1u)];
        unsigned chunk = endAll - e;
        if (chunk > 64u) chunk = 64u;
        unsigned j = 0;
        for (; j + 8u <= chunk; j += 8u) {       // full batches: no guards
            unsigned rec0 = (unsigned)__builtin_amdgcn_readlane((int)recv, (int)(j + 0));
            unsigned rec1 = (unsigned)__builtin_amdgcn_readlane((int)recv, (int)(j + 1));
            unsigned rec2 = (unsigned)__builtin_amdgcn_readlane((int)recv, (int)(j + 2));
            unsigned rec3 = (unsigned)__builtin_amdgcn_readlane((int)recv, (int)(j + 3));
            unsigned rec4 = (unsigned)__builtin_amdgcn_readlane((int)recv, (int)(j + 4));
            unsigned rec5 = (unsigned)__builtin_amdgcn_readlane((int)recv, (int)(j + 5));
            unsigned rec6 = (unsigned)__builtin_amdgcn_readlane((int)recv, (int)(j + 6));
            unsigned rec7 = (unsigned)__builtin_amdgcn_readlane((int)recv, (int)(j + 7));
            unsigned pv0 = xbu[((rec0 & 0xFFFFu) << 6) + lane];
            unsigned pv1 = xbu[((rec1 & 0xFFFFu) << 6) + lane];
            unsigned pv2 = xbu[((rec2 & 0xFFFFu) << 6) + lane];
            unsigned pv3 = xbu[((rec3 & 0xFFFFu) << 6) + lane];
            unsigned pv4 = xbu[((rec4 & 0xFFFFu) << 6) + lane];
            unsigned pv5 = xbu[((rec5 & 0xFFFFu) << 6) + lane];
            unsigned pv6 = xbu[((rec6 & 0xFFFFu) << 6) + lane];
            unsigned pv7 = xbu[((rec7 & 0xFFFFu) << 6) + lane];
            while (e >= endr) FLUSH_REL; ACCUM(rec0, pv0); ++e;
            while (e >= endr) FLUSH_REL; ACCUM(rec1, pv1); ++e;
            while (e >= endr) FLUSH_REL; ACCUM(rec2, pv2); ++e;
            while (e >= endr) FLUSH_REL; ACCUM(rec3, pv3); ++e;
            while (e >= endr) FLUSH_REL; ACCUM(rec4, pv4); ++e;
            while (e >= endr) FLUSH_REL; ACCUM(rec5, pv5); ++e;
            while (e >= endr) FLUSH_REL; ACCUM(rec6, pv6); ++e;
            while (e >= endr) FLUSH_REL; ACCUM(rec7, pv7); ++e;
        }
        for (; j < chunk; ++j) {                 // scalar tail
            unsigned rc = (unsigned)__builtin_amdgcn_readlane((int)recv, (int)j);
            unsigned pv = xbu[((rc & 0xFFFFu) << 6) + lane];
            while (e >= endr) FLUSH_REL;
            ACCUM(rc, pv);
            ++e;
        }
    }
    while (r < RR) FLUSH_REL;

#pragma unroll
    for (int b = 0; b < NBASIS; ++b)
        __builtin_nontemporal_store(cvt_pk_bf16(cb[b].x, cb[b].y),
                                    arow + b * 64 + lane);

    float s2 = 1.0f / ((sumw + 1e-8f) * fmaxf((float)deg, 1.0f));
    __builtin_nontemporal_store(cvt_pk_bf16(xt.x * s2, xt.y * s2),
                                arow + NBASIS * 64 + lane);
    __builtin_nontemporal_store(
        ((const unsigned*)(xb + (size_t)dst * DD))[lane],
        arow + (NBASIS + 1) * 64 + lane);
#undef FLUSH_REL
#undef ACCUM
}

// ---------------- tiled MFMA GEMM: double-buffered B in LDS, A register-prefetched ----------
// 2-phase pipeline: stage B(it+1) into buf^1, compute buf, ONE barrier/iter.
__global__ __launch_bounds__(256) void k_fgemm(
    const ushort* __restrict__ A2, const ushort* __restrict__ Bt3,
    const float* __restrict__ bias, const float* __restrict__ tpb,
    const float* __restrict__ gamma, const float* __restrict__ beta,
    float* __restrict__ out)
{
    __shared__ unsigned Bs[2][4096];    // 2 x 16 KB: [col 128][8 chunks x 16B], XOR-swizzled

    const int tid = threadIdx.x;
    const int w = tid >> 6, lane = tid & 63;
    const int quad = lane >> 4, l16 = lane & 15;
    const int n0 = blockIdx.x * 64;

    f32x4 acc[8];
#pragma unroll
    for (int ct = 0; ct < 8; ++ct) acc[ct] = (f32x4){0.f, 0.f, 0.f, 0.f};

    const ushort* arow = A2 + (size_t)(n0 + w * 16 + l16) * KTOT + quad * 8;
    const int srow = lane >> 3;          // 0..7 within a staging inst group
    const int sc   = lane & 7;           // physical chunk

#define STAGE(buf, itv) {                                                    \
        const int k0_ = (itv) * 64;                                          \
        _Pragma("unroll")                                                    \
        for (int i_ = 0; i_ < 4; ++i_) {                                     \
            const int cid_ = i_ * 4 + w;                                     \
            const int row_ = cid_ * 8 + srow;                                \
            const int ck_  = sc ^ (row_ & 7);                                \
            const ushort* gb_ = Bt3 + (size_t)row_ * KTOT + k0_ + ck_ * 8;   \
            __builtin_amdgcn_global_load_lds(                                \
                (const __attribute__((address_space(1))) unsigned*)gb_,      \
                (__attribute__((address_space(3))) unsigned*)&Bs[buf][cid_ * 256], \
                16, 0, 0);                                                   \
        } }

    STAGE(0, 0);
    bf16x8 afp0 = *(const bf16x8*)(arow);         // prefetch A(it=0)
    bf16x8 afp1 = *(const bf16x8*)(arow + 32);
    __syncthreads();                              // drain stage(0) + A(0)

    const int NIT = KTOT / 64;                    // 24
    for (int it = 0; it < NIT; ++it) {
        if (it + 1 < NIT) STAGE((it + 1) & 1, it + 1);   // overlaps compute below
        bf16x8 af0 = afp0, af1 = afp1;
        if (it + 1 < NIT) {                       // prefetch A(it+1)
            afp0 = *(const bf16x8*)(arow + (it + 1) * 64);
            afp1 = *(const bf16x8*)(arow + (it + 1) * 64 + 32);
        }
        const unsigned* Bp = &Bs[it & 1][0];
#pragma unroll
        for (int ct = 0; ct < 8; ++ct) {
            const int rB = ct * 16 + l16;
            bf16x8 b0 = *(const bf16x8*)&Bp[rB * 32 + ((quad ^ (rB & 7)) << 2)];
            bf16x8 b1 = *(const bf16x8*)&Bp[rB * 32 + (((4 + quad) ^ (rB & 7)) << 2)];
            acc[ct] = __builtin_amdgcn_mfma_f32_16x16x32_bf16(af0, b0, acc[ct], 0, 0, 0);
            acc[ct] = __builtin_amdgcn_mfma_f32_16x16x32_bf16(af1, b1, acc[ct], 0, 0, 0);
        }
        __syncthreads();   // drains stage(it+1)+A(it+1); all waves done reading Bs[it&1]
    }
#undef STAGE

    // ---- epilogue: bias + relu + LN (in-wave, rows rb = n0 + w*16) ----
    float bc[8], gc[8], be[8];
#pragma unroll
    for (int ct = 0; ct < 8; ++ct) {
        int col = ct * 16 + l16;
        bc[ct] = bias[col] + tpb[col];
        gc[ct] = gamma[col];
        be[ct] = beta[col];
    }
    float s[4] = {0, 0, 0, 0}, q[4] = {0, 0, 0, 0};
#pragma unroll
    for (int ct = 0; ct < 8; ++ct)
#pragma unroll
        for (int i = 0; i < 4; ++i) {
            float v = fmaxf(acc[ct][i] + bc[ct], 0.0f);
            acc[ct][i] = v;
            s[i] += v;
            q[i] = fmaf(v, v, q[i]);
        }
#pragma unroll
    for (int off = 1; off < 16; off <<= 1)
#pragma unroll
        for (int i = 0; i < 4; ++i) {
            s[i] += __shfl_xor(s[i], off, 64);
            q[i] += __shfl_xor(q[i], off, 64);
        }
#pragma unroll
    for (int i = 0; i < 4; ++i) {
        const int row = n0 + w * 16 + quad * 4 + i;
        float mu  = s[i] * (1.0f / DD);
        float var = q[i] * (1.0f / DD) - mu * mu;
        float inv = rsqrtf(var + 1e-5f);
        if (row < NN) {
#pragma unroll
            for (int ct = 0; ct < 8; ++ct)
                __builtin_nontemporal_store(
                    (acc[ct][i] - mu) * inv * gc[ct] + be[ct],
                    out + (size_t)row * DD + ct * 16 + l16);
        }
    }
}

extern "C" void kernel_launch(void* const* d_in, const int* in_sizes, int n_in,
                              void* d_out, int out_size, void* d_ws, size_t ws_size,
                              hipStream_t stream)
{
    const float* x     = (const float*)d_in[0];
    const int*   ei    = (const int*)d_in[1];
    const int*   etype = (const int*)d_in[2];
    const float* etime = (const float*)d_in[3];
    const float* basis = (const float*)d_in[4];
    const float* comp  = (const float*)d_in[5];
    const float* root  = (const float*)d_in[6];
    const float* bias  = (const float*)d_in[7];
    const float* tp_w  = (const float*)d_in[8];
    const float* tp_b  = (const float*)d_in[9];
    const float* gamma = (const float*)d_in[10];
    const float* beta  = (const float*)d_in[11];
    float* out = (float*)d_out;

    char* ws = (char*)d_ws;
    size_t off = 0;
    auto alloc = [&](size_t bytes) -> void* {
        void* p = ws + off;
        off = (off + bytes + 255) & ~(size_t)255;
        return p;
    };
    unsigned* red    = (unsigned*)alloc(64);
    unsigned* cnt    = (unsigned*)alloc((size_t)NSEG * 4);        //   3.2 MB
    unsigned* segptr = (unsigned*)alloc((size_t)NSEG * 4);        //   3.2 MB
    unsigned* part   = (unsigned*)alloc(1024 * 4);                //   4 KB
    unsigned* srcw   = (unsigned*)alloc((size_t)NE * 4);          //   6.4 MB
    ushort*   xb     = (ushort*)alloc((size_t)NN * DD * 2);       //  12.8 MB
    ushort*   Bt3    = (ushort*)alloc((size_t)DD * KTOT * 2);     //   0.39 MB
    ushort*   A2     = (ushort*)alloc((size_t)50048 * KTOT * 2);  // 153.7 MB (~180 MB total)
    (void)ws_size;

    const int* esrc = ei;
    const int* edst = ei + NE;

    hipLaunchKernelGGL(k_init, dim3(1), dim3(64), 0, stream, red);
    (void)hipMemsetAsync(cnt, 0, (size_t)NSEG * 4, stream);
    hipLaunchKernelGGL(k_pre1, dim3(1024), dim3(256), 0, stream,
                       etime, edst, etype, red, cnt);

    hipLaunchKernelGGL(k_scan1, dim3(NPART), dim3(1024), 0, stream, cnt, segptr, part);
    hipLaunchKernelGGL(k_scan2, dim3(1), dim3(1024), 0, stream, part);
    hipLaunchKernelGGL(k_scan3, dim3(NPART), dim3(1024), 0, stream, segptr, part);

    hipLaunchKernelGGL(k_pre2, dim3(1024), dim3(256), 0, stream,
                       esrc, edst, etype, etime, red, segptr, srcw);

    hipLaunchKernelGGL(k_prep, dim3((XB_ITEMS + DD * KTOT + 255) / 256), dim3(256), 0, stream,
                       x, basis, root, tp_w, xb, Bt3);

    hipLaunchKernelGGL(k_gather, dim3((NN + 3) / 4), dim3(256), 0, stream,
                       xb, srcw, segptr, red, comp, A2);

    hipLaunchKernelGGL(k_fgemm, dim3((50048 + 63) / 64), dim3(256), 0, stream,
                       A2, Bt3, bias, tp_b, gamma, beta, out);
}

// Round 3
// 391.860 us; speedup vs baseline: 1.1504x; 1.0752x over previous
//
#include <hip/hip_runtime.h>
#include <hip/hip_bf16.h>
#include <math.h>

#define NN 50000
#define DD 128
#define RR 16
#define NBASIS 10
#define NE 1600000
#define NSEG (NN * RR)                  // 800000 segments (dst,rel)
#define NPART ((NSEG + 1023) / 1024)    // 782
#define NSLICE 12                       // 10 basis + time + root  (basis-space compressed)
#define KTOT (NSLICE * DD)              // 1536
#define DECAY 0.1f

typedef short bf16x8 __attribute__((ext_vector_type(8)));
typedef float f32x4 __attribute__((ext_vector_type(4)));
typedef float f32x2 __attribute__((ext_vector_type(2)));

__device__ __forceinline__ ushort f2b(float f) {
    unsigned u = __float_as_uint(f);
    unsigned r = (u + 0x7FFFu + ((u >> 16) & 1u)) >> 16;
    return (ushort)r;
}
// packed f32->bf16 RNE convert (gfx950), lo -> bits[15:0], hi -> bits[31:16]
__device__ __forceinline__ unsigned cvt_pk_bf16(float lo, float hi) {
    unsigned r;
    asm("v_cvt_pk_bf16_f32 %0, %1, %2" : "=v"(r) : "v"(lo), "v"(hi));
    return r;
}

// ---------------- reduction slots ----------------
__global__ void k_init(unsigned* red) {
    if (threadIdx.x == 0) {
        red[0] = 0u;              // max(t) bits (t>=0: uint order == float order)
        red[1] = 0x7F800000u;     // min(t) = +inf
        ((float*)red)[2] = 0.0f;  // sum of unnormalized w
    }
}

// ---------------- grid-stride: minmax + histogram + PER-EDGE RANK ----------------
// The histogram atomic's return value IS the edge's rank within its segment:
// keep it (sequential u16 stream) so k_pre2 needs no atomics at all.
__global__ __launch_bounds__(256) void k_pre1(const float* __restrict__ t,
                                              const int* __restrict__ edst,
                                              const int* __restrict__ etype,
                                              unsigned* __restrict__ red,
                                              unsigned* __restrict__ cnt,
                                              unsigned* __restrict__ segarr,
                                              ushort* __restrict__ rank) {
    __shared__ float smx[4], smn[4];
    const int tid = threadIdx.x;
    float mx = 0.0f, mn = 1e30f;
    const int stride = gridDim.x * 256;
    for (int e = blockIdx.x * 256 + tid; e < NE; e += stride) {
        float v = __builtin_nontemporal_load(t + e);
        int d   = __builtin_nontemporal_load(edst + e);
        int ty  = __builtin_nontemporal_load(etype + e);
        mx = fmaxf(mx, v);
        mn = fminf(mn, v);
        int seg = d * RR + ty;
        unsigned rk = atomicAdd(&cnt[seg], 1u);
        __builtin_nontemporal_store((unsigned)seg, segarr + e);
        __builtin_nontemporal_store((ushort)rk, rank + e);
    }
    for (int o = 32; o >= 1; o >>= 1) {
        mx = fmaxf(mx, __shfl_down(mx, o, 64));
        mn = fminf(mn, __shfl_down(mn, o, 64));
    }
    if ((tid & 63) == 0) { smx[tid >> 6] = mx; smn[tid >> 6] = mn; }
    __syncthreads();
    if (tid == 0) {
        mx = fmaxf(fmaxf(smx[0], smx[1]), fmaxf(smx[2], smx[3]));
        mn = fminf(fminf(smn[0], smn[1]), fminf(smn[2], smn[3]));
        atomicMax(&red[0], __float_as_uint(mx));
        atomicMin(&red[1], __float_as_uint(mn));
    }
}

// ---------------- hierarchical exclusive scan over cnt[NSEG] ----------------
__global__ __launch_bounds__(1024) void k_scan1(const unsigned* __restrict__ cnt,
                                                unsigned* __restrict__ segptr,
                                                unsigned* __restrict__ part) {
    __shared__ unsigned sh[1024];
    int tid = threadIdx.x;
    int i = blockIdx.x * 1024 + tid;
    unsigned v = (i < NSEG) ? cnt[i] : 0u;
    sh[tid] = v;
    __syncthreads();
    for (int off = 1; off < 1024; off <<= 1) {
        unsigned t = (tid >= off) ? sh[tid - off] : 0u;
        __syncthreads();
        sh[tid] += t;
        __syncthreads();
    }
    if (i < NSEG) segptr[i] = sh[tid] - v;       // exclusive, block-local
    if (tid == 1023) part[blockIdx.x] = sh[1023];
}

__global__ __launch_bounds__(1024) void k_scan2(unsigned* __restrict__ part) {
    __shared__ unsigned sh[1024];
    int tid = threadIdx.x;
    unsigned v = (tid < NPART) ? part[tid] : 0u;
    sh[tid] = v;
    __syncthreads();
    for (int off = 1; off < 1024; off <<= 1) {
        unsigned t = (tid >= off) ? sh[tid - off] : 0u;
        __syncthreads();
        sh[tid] += t;
        __syncthreads();
    }
    if (tid < NPART) part[tid] = sh[tid] - v;    // exclusive
}

__global__ __launch_bounds__(1024) void k_scan3(unsigned* __restrict__ segptr,
                                                const unsigned* __restrict__ part) {
    int i = blockIdx.x * 1024 + threadIdx.x;
    if (i < NSEG) segptr[i] += part[i >> 10];
    if (blockIdx.x == 0 && threadIdx.x == 0) segptr[NSEG] = NE;  // sentinel
}

// ---------------- grid-stride: sum of weights + ATOMIC-FREE reorder ----------------
// pos = segptr[seg] + rank[e]: pure loads (segptr read-shared across XCDs = cheap),
// no RMW round-trip on the critical path. segptr stays pristine (starts).
__global__ __launch_bounds__(256) void k_pre2(const int* __restrict__ esrc,
                                              const float* __restrict__ etime,
                                              const unsigned* __restrict__ segarr,
                                              const ushort* __restrict__ rank,
                                              unsigned* __restrict__ red,
                                              const unsigned* __restrict__ segptr,
                                              unsigned* __restrict__ srcw) {
    __shared__ float ssum[4];
    const int tid = threadIdx.x;
    const float tmax = __uint_as_float(red[0]);
    const float tmin = __uint_as_float(red[1]);
    const float rtd = -DECAY / (tmax - tmin + 1e-8f);
    float s = 0.0f;
    const int stride = gridDim.x * 256;
    for (int e = blockIdx.x * 256 + tid; e < NE; e += stride) {
        float tv    = __builtin_nontemporal_load(etime + e);
        int sv      = __builtin_nontemporal_load(esrc + e);
        unsigned sg = __builtin_nontemporal_load(segarr + e);
        unsigned rk = __builtin_nontemporal_load(rank + e);
        float w = __expf((tmax - tv) * rtd);     // arg in [-0.1,0]: fast path safe
        s += w;
        unsigned pos = segptr[sg] + rk;
        srcw[pos] = (unsigned)(sv & 0xFFFF) | ((unsigned)f2b(w) << 16);
    }
    for (int o = 32; o >= 1; o >>= 1) s += __shfl_down(s, o, 64);
    if ((tid & 63) == 0) ssum[tid >> 6] = s;
    __syncthreads();
    if (tid == 0)
        atomicAdd(((float*)red) + 2, ssum[0] + ssum[1] + ssum[2] + ssum[3]);
}

// ---------------- fused: x->bf16 and build Bt3[j][k] bf16 (k = slice*128+d) ----------------
// Basis-compressed B: slices 0..9 = basis[b] (no comp mixing), 10 = tp_w, 11 = root.
#define XB_ITEMS (NN * (DD / 4))
__global__ __launch_bounds__(256) void k_prep(const float* __restrict__ x,
                                              const float* __restrict__ basis,
                                              const float* __restrict__ root,
                                              const float* __restrict__ tp_w,
                                              ushort* __restrict__ xb,
                                              ushort* __restrict__ Bt3) {
    int idx = blockIdx.x * 256 + threadIdx.x;
    if (idx < XB_ITEMS) {
        float4 v = ((const float4*)x)[idx];
        uint2 o;
        o.x = cvt_pk_bf16(v.x, v.y);
        o.y = cvt_pk_bf16(v.z, v.w);
        ((uint2*)xb)[idx] = o;
        return;
    }
    int bidx = idx - XB_ITEMS;
    if (bidx >= DD * KTOT) return;
    int j = bidx / KTOT, k = bidx - j * KTOT;
    int s = k >> 7, d = k & 127;
    float v;
    if (s < NBASIS) {
        v = basis[(s * DD + d) * DD + j];
    } else if (s == NBASIS) {
        v = tp_w[d * DD + j];
    } else {
        v = root[d * DD + j];
    }
    Bt3[bidx] = f2b(v);
}

// ---------------- gather-aggregate: one wave per dst, SCALAR bookkeeping ----------------
// segptr now holds exclusive STARTS (with sentinel at NSEG): start=segptr[s0],
// end of rel r = segptr[s0+r+1].
__global__ __launch_bounds__(256) void k_gather(
    const ushort* __restrict__ xb, const unsigned* __restrict__ srcw,
    const unsigned* __restrict__ segptr, const unsigned* __restrict__ red,
    const float* __restrict__ comp,
    ushort* __restrict__ A2)
{
    const int wave = threadIdx.x >> 6, lane = threadIdx.x & 63;
    int dst0 = blockIdx.x * 4 + wave;
    if (dst0 >= NN) return;
    const int dst = __builtin_amdgcn_readfirstlane(dst0);
    const float sumw = ((const float*)red)[2];
    const unsigned s0 = (unsigned)dst * RR;
    const unsigned start = segptr[s0];
    const unsigned endAll = segptr[s0 + RR];
    const unsigned deg = endAll - start;
    unsigned* arow = (unsigned*)(A2 + (size_t)dst * KTOT);
    const unsigned* xbu = (const unsigned*)xb;    // 32-bit dword offsets from here

    f32x2 cb[NBASIS];
#pragma unroll
    for (int b = 0; b < NBASIS; ++b) cb[b] = (f32x2){0.f, 0.f};
    f32x2 acc = {0.f, 0.f}, xt = {0.f, 0.f};

    int r = 0;
    unsigned scur = start;
    unsigned endr = segptr[s0 + 1];
    unsigned e = start;

#define FLUSH_REL {                                                          \
        float scl = (endr > scur) ? (1.0f / (float)(endr - scur)) : 0.0f;    \
        f32x2 t = acc * scl;                                                 \
        _Pragma("unroll")                                                    \
        for (int b = 0; b < NBASIS; ++b)                                     \
            cb[b] += t * comp[r * NBASIS + b];                               \
        acc = (f32x2){0.f, 0.f}; scur = endr; ++r;                           \
        endr = (r < RR) ? segptr[s0 + r + 1] : 0xFFFFFFFFu; }

#define ACCUM(recq, pvq) {                                                   \
        float wgt = __uint_as_float((recq) & 0xFFFF0000u);                   \
        f32x2 v;                                                             \
        v.x = __uint_as_float((pvq) << 16);                                  \
        v.y = __uint_as_float((pvq) & 0xFFFF0000u);                          \
        acc += v;                                                            \
        xt += v * wgt; }

    while (e < endAll) {
        unsigned idx = e + (unsigned)lane;
        unsigned recv = srcw[(idx < endAll) ? idx : (endAll - 1u)];
        unsigned chunk = endAll - e;
        if (chunk > 64u) chunk = 64u;
        unsigned j = 0;
        for (; j + 8u <= chunk; j += 8u) {       // full batches: no guards
            unsigned rec0 = (unsigned)__builtin_amdgcn_readlane((int)recv, (int)(j + 0));
            unsigned rec1 = (unsigned)__builtin_amdgcn_readlane((int)recv, (int)(j + 1));
            unsigned rec2 = (unsigned)__builtin_amdgcn_readlane((int)recv, (int)(j + 2));
            unsigned rec3 = (unsigned)__builtin_amdgcn_readlane((int)recv, (int)(j + 3));
            unsigned rec4 = (unsigned)__builtin_amdgcn_readlane((int)recv, (int)(j + 4));
            unsigned rec5 = (unsigned)__builtin_amdgcn_readlane((int)recv, (int)(j + 5));
            unsigned rec6 = (unsigned)__builtin_amdgcn_readlane((int)recv, (int)(j + 6));
            unsigned rec7 = (unsigned)__builtin_amdgcn_readlane((int)recv, (int)(j + 7));
            unsigned pv0 = xbu[((rec0 & 0xFFFFu) << 6) + lane];
            unsigned pv1 = xbu[((rec1 & 0xFFFFu) << 6) + lane];
            unsigned pv2 = xbu[((rec2 & 0xFFFFu) << 6) + lane];
            unsigned pv3 = xbu[((rec3 & 0xFFFFu) << 6) + lane];
            unsigned pv4 = xbu[((rec4 & 0xFFFFu) << 6) + lane];
            unsigned pv5 = xbu[((rec5 & 0xFFFFu) << 6) + lane];
            unsigned pv6 = xbu[((rec6 & 0xFFFFu) << 6) + lane];
            unsigned pv7 = xbu[((rec7 & 0xFFFFu) << 6) + lane];
            while (e >= endr) FLUSH_REL; ACCUM(rec0, pv0); ++e;
            while (e >= endr) FLUSH_REL; ACCUM(rec1, pv1); ++e;
            while (e >= endr) FLUSH_REL; ACCUM(rec2, pv2); ++e;
            while (e >= endr) FLUSH_REL; ACCUM(rec3, pv3); ++e;
            while (e >= endr) FLUSH_REL; ACCUM(rec4, pv4); ++e;
            while (e >= endr) FLUSH_REL; ACCUM(rec5, pv5); ++e;
            while (e >= endr) FLUSH_REL; ACCUM(rec6, pv6); ++e;
            while (e >= endr) FLUSH_REL; ACCUM(rec7, pv7); ++e;
        }
        for (; j < chunk; ++j) {                 // scalar tail
            unsigned rc = (unsigned)__builtin_amdgcn_readlane((int)recv, (int)j);
            unsigned pv = xbu[((rc & 0xFFFFu) << 6) + lane];
            while (e >= endr) FLUSH_REL;
            ACCUM(rc, pv);
            ++e;
        }
    }
    while (r < RR) FLUSH_REL;

#pragma unroll
    for (int b = 0; b < NBASIS; ++b)
        __builtin_nontemporal_store(cvt_pk_bf16(cb[b].x, cb[b].y),
                                    arow + b * 64 + lane);

    float s2 = 1.0f / ((sumw + 1e-8f) * fmaxf((float)deg, 1.0f));
    __builtin_nontemporal_store(cvt_pk_bf16(xt.x * s2, xt.y * s2),
                                arow + NBASIS * 64 + lane);
    __builtin_nontemporal_store(
        ((const unsigned*)(xb + (size_t)dst * DD))[lane],
        arow + (NBASIS + 1) * 64 + lane);
#undef FLUSH_REL
#undef ACCUM
}

// ---------------- tiled MFMA GEMM: double-buffered B in LDS, A register-prefetched ----------
// 2-phase pipeline: stage B(it+1) into buf^1, compute buf, ONE barrier/iter.
__global__ __launch_bounds__(256) void k_fgemm(
    const ushort* __restrict__ A2, const ushort* __restrict__ Bt3,
    const float* __restrict__ bias, const float* __restrict__ tpb,
    const float* __restrict__ gamma, const float* __restrict__ beta,
    float* __restrict__ out)
{
    __shared__ unsigned Bs[2][4096];    // 2 x 16 KB: [col 128][8 chunks x 16B], XOR-swizzled

    const int tid = threadIdx.x;
    const int w = tid >> 6, lane = tid & 63;
    const int quad = lane >> 4, l16 = lane & 15;
    const int n0 = blockIdx.x * 64;

    f32x4 acc[8];
#pragma unroll
    for (int ct = 0; ct < 8; ++ct) acc[ct] = (f32x4){0.f, 0.f, 0.f, 0.f};

    const ushort* arow = A2 + (size_t)(n0 + w * 16 + l16) * KTOT + quad * 8;
    const int srow = lane >> 3;          // 0..7 within a staging inst group
    const int sc   = lane & 7;           // physical chunk

#define STAGE(buf, itv) {                                                    \
        const int k0_ = (itv) * 64;                                          \
        _Pragma("unroll")                                                    \
        for (int i_ = 0; i_ < 4; ++i_) {                                     \
            const int cid_ = i_ * 4 + w;                                     \
            const int row_ = cid_ * 8 + srow;                                \
            const int ck_  = sc ^ (row_ & 7);                                \
            const ushort* gb_ = Bt3 + (size_t)row_ * KTOT + k0_ + ck_ * 8;   \
            __builtin_amdgcn_global_load_lds(                                \
                (const __attribute__((address_space(1))) unsigned*)gb_,      \
                (__attribute__((address_space(3))) unsigned*)&Bs[buf][cid_ * 256], \
                16, 0, 0);                                                   \
        } }

    STAGE(0, 0);
    bf16x8 afp0 = *(const bf16x8*)(arow);         // prefetch A(it=0)
    bf16x8 afp1 = *(const bf16x8*)(arow + 32);
    __syncthreads();                              // drain stage(0) + A(0)

    const int NIT = KTOT / 64;                    // 24
    for (int it = 0; it < NIT; ++it) {
        if (it + 1 < NIT) STAGE((it + 1) & 1, it + 1);   // overlaps compute below
        bf16x8 af0 = afp0, af1 = afp1;
        if (it + 1 < NIT) {                       // prefetch A(it+1)
            afp0 = *(const bf16x8*)(arow + (it + 1) * 64);
            afp1 = *(const bf16x8*)(arow + (it + 1) * 64 + 32);
        }
        const unsigned* Bp = &Bs[it & 1][0];
#pragma unroll
        for (int ct = 0; ct < 8; ++ct) {
            const int rB = ct * 16 + l16;
            bf16x8 b0 = *(const bf16x8*)&Bp[rB * 32 + ((quad ^ (rB & 7)) << 2)];
            bf16x8 b1 = *(const bf16x8*)&Bp[rB * 32 + (((4 + quad) ^ (rB & 7)) << 2)];
            acc[ct] = __builtin_amdgcn_mfma_f32_16x16x32_bf16(af0, b0, acc[ct], 0, 0, 0);
            acc[ct] = __builtin_amdgcn_mfma_f32_16x16x32_bf16(af1, b1, acc[ct], 0, 0, 0);
        }
        __syncthreads();   // drains stage(it+1)+A(it+1); all waves done reading Bs[it&1]
    }
#undef STAGE

    // ---- epilogue: bias + relu + LN (in-wave, rows rb = n0 + w*16) ----
    float bc[8], gc[8], be[8];
#pragma unroll
    for (int ct = 0; ct < 8; ++ct) {
        int col = ct * 16 + l16;
        bc[ct] = bias[col] + tpb[col];
        gc[ct] = gamma[col];
        be[ct] = beta[col];
    }
    float s[4] = {0, 0, 0, 0}, q[4] = {0, 0, 0, 0};
#pragma unroll
    for (int ct = 0; ct < 8; ++ct)
#pragma unroll
        for (int i = 0; i < 4; ++i) {
            float v = fmaxf(acc[ct][i] + bc[ct], 0.0f);
            acc[ct][i] = v;
            s[i] += v;
            q[i] = fmaf(v, v, q[i]);
        }
#pragma unroll
    for (int off = 1; off < 16; off <<= 1)
#pragma unroll
        for (int i = 0; i < 4; ++i) {
            s[i] += __shfl_xor(s[i], off, 64);
            q[i] += __shfl_xor(q[i], off, 64);
        }
#pragma unroll
    for (int i = 0; i < 4; ++i) {
        const int row = n0 + w * 16 + quad * 4 + i;
        float mu  = s[i] * (1.0f / DD);
        float var = q[i] * (1.0f / DD) - mu * mu;
        float inv = rsqrtf(var + 1e-5f);
        if (row < NN) {
#pragma unroll
            for (int ct = 0; ct < 8; ++ct)
                __builtin_nontemporal_store(
                    (acc[ct][i] - mu) * inv * gc[ct] + be[ct],
                    out + (size_t)row * DD + ct * 16 + l16);
        }
    }
}

extern "C" void kernel_launch(void* const* d_in, const int* in_sizes, int n_in,
                              void* d_out, int out_size, void* d_ws, size_t ws_size,
                              hipStream_t stream)
{
    const float* x     = (const float*)d_in[0];
    const int*   ei    = (const int*)d_in[1];
    const int*   etype = (const int*)d_in[2];
    const float* etime = (const float*)d_in[3];
    const float* basis = (const float*)d_in[4];
    const float* comp  = (const float*)d_in[5];
    const float* root  = (const float*)d_in[6];
    const float* bias  = (const float*)d_in[7];
    const float* tp_w  = (const float*)d_in[8];
    const float* tp_b  = (const float*)d_in[9];
    const float* gamma = (const float*)d_in[10];
    const float* beta  = (const float*)d_in[11];
    float* out = (float*)d_out;

    char* ws = (char*)d_ws;
    size_t off = 0;
    auto alloc = [&](size_t bytes) -> void* {
        void* p = ws + off;
        off = (off + bytes + 255) & ~(size_t)255;
        return p;
    };
    unsigned* red    = (unsigned*)alloc(64);
    unsigned* cnt    = (unsigned*)alloc((size_t)NSEG * 4);        //   3.2 MB
    unsigned* segptr = (unsigned*)alloc((size_t)(NSEG + 1) * 4);  //   3.2 MB (+sentinel)
    unsigned* part   = (unsigned*)alloc(1024 * 4);                //   4 KB
    unsigned* srcw   = (unsigned*)alloc((size_t)NE * 4);          //   6.4 MB
    unsigned* segarr = (unsigned*)alloc((size_t)NE * 4);          //   6.4 MB
    ushort*   rank   = (ushort*)alloc((size_t)NE * 2);            //   3.2 MB
    ushort*   xb     = (ushort*)alloc((size_t)NN * DD * 2);       //  12.8 MB
    ushort*   Bt3    = (ushort*)alloc((size_t)DD * KTOT * 2);     //   0.39 MB
    ushort*   A2     = (ushort*)alloc((size_t)50048 * KTOT * 2);  // 153.7 MB (~190 MB total)
    (void)ws_size;

    const int* esrc = ei;
    const int* edst = ei + NE;

    hipLaunchKernelGGL(k_init, dim3(1), dim3(64), 0, stream, red);
    (void)hipMemsetAsync(cnt, 0, (size_t)NSEG * 4, stream);
    hipLaunchKernelGGL(k_pre1, dim3(1024), dim3(256), 0, stream,
                       etime, edst, etype, red, cnt, segarr, rank);

    hipLaunchKernelGGL(k_scan1, dim3(NPART), dim3(1024), 0, stream, cnt, segptr, part);
    hipLaunchKernelGGL(k_scan2, dim3(1), dim3(1024), 0, stream, part);
    hipLaunchKernelGGL(k_scan3, dim3(NPART), dim3(1024), 0, stream, segptr, part);

    hipLaunchKernelGGL(k_pre2, dim3(1024), dim3(256), 0, stream,
                       esrc, etime, segarr, rank, red, segptr, srcw);

    hipLaunchKernelGGL(k_prep, dim3((XB_ITEMS + DD * KTOT + 255) / 256), dim3(256), 0, stream,
                       x, basis, root, tp_w, xb, Bt3);

    hipLaunchKernelGGL(k_gather, dim3((NN + 3) / 4), dim3(256), 0, stream,
                       xb, srcw, segptr, red, comp, A2);

    hipLaunchKernelGGL(k_fgemm, dim3((50048 + 63) / 64), dim3(256), 0, stream,
                       A2, Bt3, bias, tp_b, gamma, beta, out);
}